// Round 1
// baseline (323.379 us; speedup 1.0000x reference)
//
#include <hip/hip_runtime.h>
#include <math.h>

#define NBINS 1001
#define KQ 127
#define HALFB 500
#define SEPS 1e-4f
#define NCAND 438   // i = 63 .. 500
#define IMIN 63

// ---------- ws layout (uint words) ----------
// ws_u[0]          : absmax bits (float as uint; |x|>=0 so uint order == float order)
// ws_u[4..4+1001)  : histogram counts (uint)
// ws_u[1028..]     : divergence[438] (float)

static __device__ __forceinline__ float edge_at(int j, float stepv, float negabs) {
    // mimic linspace: edges[j] = j*step + (-absmax), no fma contraction
    return __fadd_rn(__fmul_rn((float)j, stepv), negabs);
}

// ---------------- block reduction helpers (blockDim.x == 256) ----------------
static __device__ __forceinline__ double blockReduceSumD(double v, double* buf) {
    const int tid = threadIdx.x;
    __syncthreads();
    buf[tid] = v;
    __syncthreads();
    for (int s = 128; s > 0; s >>= 1) {
        if (tid < s) buf[tid] += buf[tid + s];
        __syncthreads();
    }
    return buf[0];
}

static __device__ __forceinline__ double blockReduceMaxD(double v, double* buf) {
    const int tid = threadIdx.x;
    __syncthreads();
    buf[tid] = v;
    __syncthreads();
    for (int s = 128; s > 0; s >>= 1) {
        if (tid < s) buf[tid] = fmax(buf[tid], buf[tid + s]);
        __syncthreads();
    }
    return buf[0];
}

// ---------------- kernels ----------------

__global__ void init_kernel(unsigned int* ws_u) {
    int t = threadIdx.x;             // single block of 1024
    if (t == 0) ws_u[0] = 0u;
    if (t < NBINS) ws_u[4 + t] = 0u;
}

__global__ __launch_bounds__(256) void absmax_kernel(const float* __restrict__ x,
                                                     long long n,
                                                     unsigned int* absmax_bits) {
    __shared__ float red[256];
    float m = 0.f;
    long long idx = (long long)blockIdx.x * blockDim.x + threadIdx.x;
    long long stride = (long long)gridDim.x * blockDim.x;
    const float4* x4 = (const float4*)x;
    long long n4 = n >> 2;
    for (long long i = idx; i < n4; i += stride) {
        float4 v = x4[i];
        m = fmaxf(m, fmaxf(fmaxf(fabsf(v.x), fabsf(v.y)), fmaxf(fabsf(v.z), fabsf(v.w))));
    }
    for (long long i = (n4 << 2) + idx; i < n; i += stride)
        m = fmaxf(m, fabsf(x[i]));
    red[threadIdx.x] = m;
    __syncthreads();
    for (int s = 128; s > 0; s >>= 1) {
        if (threadIdx.x < s) red[threadIdx.x] = fmaxf(red[threadIdx.x], red[threadIdx.x + s]);
        __syncthreads();
    }
    if (threadIdx.x == 0) atomicMax(absmax_bits, __float_as_uint(red[0]));
}

static __device__ __forceinline__ void bin_one(float v, float absmax, float negabs,
                                               float stepv, float inv, unsigned int* sh) {
    float t = __fmul_rn(__fadd_rn(v, absmax), inv);
    int b = (int)t;
    b = b < 0 ? 0 : (b > NBINS - 1 ? NBINS - 1 : b);
    // correct to exact searchsorted semantics against edges[j] = j*step - absmax
    while (b > 0 && v < edge_at(b, stepv, negabs)) --b;
    while (b < NBINS - 1 && v >= edge_at(b + 1, stepv, negabs)) ++b;
    atomicAdd(&sh[b], 1u);
}

__global__ __launch_bounds__(256) void hist_kernel(const float* __restrict__ x,
                                                   long long n,
                                                   const unsigned int* __restrict__ absmax_bits,
                                                   unsigned int* __restrict__ hist) {
    __shared__ unsigned int sh[NBINS];
    for (int i = threadIdx.x; i < NBINS; i += blockDim.x) sh[i] = 0u;
    __syncthreads();

    float absmax = __uint_as_float(*absmax_bits);
    float negabs = -absmax;
    float stepv = __fdiv_rn(__fmul_rn(2.0f, absmax), 1001.0f);
    float inv = __fdiv_rn(1001.0f, __fmul_rn(2.0f, absmax));

    long long idx = (long long)blockIdx.x * blockDim.x + threadIdx.x;
    long long stride = (long long)gridDim.x * blockDim.x;
    const float4* x4 = (const float4*)x;
    long long n4 = n >> 2;
    for (long long i = idx; i < n4; i += stride) {
        float4 v = x4[i];
        bin_one(v.x, absmax, negabs, stepv, inv, sh);
        bin_one(v.y, absmax, negabs, stepv, inv, sh);
        bin_one(v.z, absmax, negabs, stepv, inv, sh);
        bin_one(v.w, absmax, negabs, stepv, inv, sh);
    }
    for (long long i = (n4 << 2) + idx; i < n; i += stride)
        bin_one(x[i], absmax, negabs, stepv, inv, sh);

    __syncthreads();
    for (int i = threadIdx.x; i < NBINS; i += blockDim.x)
        if (sh[i]) atomicAdd(&hist[i], sh[i]);
}

__global__ __launch_bounds__(256) void cand_kernel(const unsigned int* __restrict__ hist,
                                                   float* __restrict__ divg) {
    const int i = IMIN + (int)blockIdx.x;   // 63..500
    const int L = 2 * i + 1;                // 127..1001
    const int start = HALFB - i;
    const int stop = start + L;
    const int m = L / KQ;                   // 1..7
    const int tid = threadIdx.x;

    __shared__ float s_qb[KQ];
    __shared__ int s_norm[KQ];
    __shared__ double dbuf[256];

    if (tid < KQ) { s_qb[tid] = 0.f; s_norm[tid] = 0; }

    // left = sum hist[0:start], right = sum hist[stop:1001]
    float lsum = 0.f, rsum = 0.f;
    for (int k = tid; k < start; k += 256) lsum += (float)hist[k];
    for (int k = stop + tid; k < NBINS; k += 256) rsum += (float)hist[k];
    float left = (float)blockReduceSumD((double)lsum, dbuf);
    float right = (float)blockReduceSumD((double)rsum, dbuf);

    // pass 1: sliced values, p-logit precursors, segment sums
    float sl[4], ppre[4];
    float zp = 0.f;           // count of p==0 among valid
    float maxppre = -INFINITY;
#pragma unroll
    for (int j = 0; j < 4; ++j) {
        int k = tid + 256 * j;
        sl[j] = 0.f; ppre[j] = 0.f;
        if (k < L) {
            float s = (float)hist[start + k];
            sl[j] = s;
            int seg = k / m; if (seg > KQ - 1) seg = KQ - 1;
            atomicAdd(&s_qb[seg], s);
            if (s != 0.f && k != L - 1) atomicAdd(&s_norm[seg], 1);
            float p = s;
            if (k == 0) p += left;
            if (k == L - 1) p += right;
            float pp = (p == 0.f) ? SEPS : p;   // p + EPS*is_zero
            ppre[j] = pp;
            if (p == 0.f) zp += 1.f;
            maxppre = fmaxf(maxppre, pp);
        }
    }
    __syncthreads();   // s_qb / s_norm final

    float n_zeros_p = (float)blockReduceSumD((double)zp, dbuf);
    float maxp = (float)blockReduceMaxD((double)maxppre, dbuf);
    int nnzq = (int)blockReduceSumD(tid < KQ ? (double)s_norm[tid] : 0.0, dbuf);

    // smoothing constants, f32 as in reference
    float n_nz_p = (float)L - n_zeros_p;
    float eps1p = SEPS * n_zeros_p / fmaxf(n_nz_p, 1.0f);
    float cp = eps1p * n_nz_p;

    float n_zeros_q = (float)L - (float)nnzq;   // q nonzero <=> (sliced!=0 && k!=L-1)
    float n_nz_qf = (float)L - n_zeros_q;
    float eps1q = SEPS * n_zeros_q / fmaxf(n_nz_qf, 1.0f);
    float cq = eps1q * n_nz_qf;

    // pass 2: q-logit precursors
    float qpre[4];
    float maxqpre = -INFINITY;
#pragma unroll
    for (int j = 0; j < 4; ++j) {
        int k = tid + 256 * j;
        qpre[j] = 0.f;
        if (k < L) {
            float s = sl[j];
            int seg = k / m; if (seg > KQ - 1) seg = KQ - 1;
            float qv = 0.f;
            int nk = s_norm[seg];
            if (s != 0.f && k != L - 1 && nk > 0) qv = s_qb[seg] / (float)nk;
            float qq = (qv == 0.f) ? SEPS : qv;
            qpre[j] = qq;
            maxqpre = fmaxf(maxqpre, qq);
        }
    }
    float maxq = (float)blockReduceMaxD((double)maxqpre, dbuf);
    float maxplog = maxp - cp;
    float maxqlog = maxq - cq;

    // pass 3: logsumexp sums
    double sp = 0.0, sq = 0.0;
#pragma unroll
    for (int j = 0; j < 4; ++j) {
        int k = tid + 256 * j;
        if (k < L) {
            sp += (double)expf((ppre[j] - cp) - maxplog);
            sq += (double)expf((qpre[j] - cq) - maxqlog);
        }
    }
    double Sp = blockReduceSumD(sp, dbuf);
    double Sq = blockReduceSumD(sq, dbuf);
    float lZp = maxplog + (float)log(Sp);
    float lZq = maxqlog + (float)log(Sq);

    // pass 4: KL
    double kll = 0.0;
#pragma unroll
    for (int j = 0; j < 4; ++j) {
        int k = tid + 256 * j;
        if (k < L) {
            float pl = ppre[j] - cp;
            float ql = qpre[j] - cq;
            float lp = pl - lZp;
            float lq = ql - lZq;
            kll += (double)(expf(lp) * (lp - lq));
        }
    }
    double KL = blockReduceSumD(kll, dbuf);
    if (tid == 0) divg[blockIdx.x] = (nnzq > 0) ? (float)KL : INFINITY;
}

__global__ void argmin_kernel(const float* __restrict__ divg,
                              const unsigned int* __restrict__ absmax_bits,
                              float* __restrict__ out) {
    __shared__ float vals[512];
    __shared__ int idxs[512];
    int tid = threadIdx.x;
    vals[tid] = (tid < NCAND) ? divg[tid] : INFINITY;
    idxs[tid] = tid;
    __syncthreads();
    for (int s = 256; s > 0; s >>= 1) {
        if (tid < s) {
            float a = vals[tid], b = vals[tid + s];
            int ia = idxs[tid], ib = idxs[tid + s];
            if (b < a || (b == a && ib < ia)) { vals[tid] = b; idxs[tid] = ib; }
        }
        __syncthreads();
    }
    if (tid == 0) {
        int i = IMIN + idxs[0];
        int stop = HALFB + i + 1;
        float absmax = __uint_as_float(*absmax_bits);
        float stepv = __fdiv_rn(__fmul_rn(2.0f, absmax), 1001.0f);
        out[0] = __fadd_rn(__fmul_rn((float)stop, stepv), -absmax);
    }
}

extern "C" void kernel_launch(void* const* d_in, const int* in_sizes, int n_in,
                              void* d_out, int out_size, void* d_ws, size_t ws_size,
                              hipStream_t stream) {
    const float* x = (const float*)d_in[0];
    long long n = (long long)in_sizes[0];

    unsigned int* ws_u = (unsigned int*)d_ws;
    unsigned int* absmax_bits = ws_u;                 // word 0
    unsigned int* hist = ws_u + 4;                    // words 4 .. 4+1001
    float* divg = (float*)(ws_u + 1028);              // words 1028 .. 1028+438
    float* out = (float*)d_out;

    hipLaunchKernelGGL(init_kernel, dim3(1), dim3(1024), 0, stream, ws_u);
    hipLaunchKernelGGL(absmax_kernel, dim3(2048), dim3(256), 0, stream, x, n, absmax_bits);
    hipLaunchKernelGGL(hist_kernel, dim3(2048), dim3(256), 0, stream, x, n, absmax_bits, hist);
    hipLaunchKernelGGL(cand_kernel, dim3(NCAND), dim3(256), 0, stream, hist, divg);
    hipLaunchKernelGGL(argmin_kernel, dim3(1), dim3(512), 0, stream, divg, absmax_bits, out);
}

// Round 2
// 258.131 us; speedup vs baseline: 1.2528x; 1.2528x over previous
//
#include <hip/hip_runtime.h>
#include <math.h>

#define NBINS 1001
#define KQ 127
#define HALFB 500
#define SEPS 1e-4f
#define NCAND 438   // i = 63 .. 500
#define IMIN 63

// ---------- ws layout (uint words) ----------
// ws_u[0]          : absmax bits (float as uint; |x|>=0 so uint order == float order)
// ws_u[4..4+1001)  : histogram counts (uint)
// ws_u[1028..]     : divergence[438] (float)

static __device__ __forceinline__ float edge_at(int j, float stepv, float negabs) {
    // linspace semantics: edges[j] = j*step + (-absmax), separate rn mul/add (no fma)
    return __fadd_rn(__fmul_rn((float)j, stepv), negabs);
}

// ---------------- block reduction helpers (blockDim.x == 256 = 4 waves) ----------------
static __device__ __forceinline__ void blockSum2(double& a, double& b, double* s8) {
    for (int s = 32; s > 0; s >>= 1) {
        a += __shfl_down(a, s, 64);
        b += __shfl_down(b, s, 64);
    }
    const int w = threadIdx.x >> 6, l = threadIdx.x & 63;
    __syncthreads();                 // protect buffer reuse across calls
    if (l == 0) { s8[w] = a; s8[4 + w] = b; }
    __syncthreads();
    a = (s8[0] + s8[1]) + (s8[2] + s8[3]);
    b = (s8[4] + s8[5]) + (s8[6] + s8[7]);
}

static __device__ __forceinline__ double blockSum1(double a, double* s8) {
    for (int s = 32; s > 0; s >>= 1) a += __shfl_down(a, s, 64);
    const int w = threadIdx.x >> 6, l = threadIdx.x & 63;
    __syncthreads();
    if (l == 0) s8[w] = a;
    __syncthreads();
    return (s8[0] + s8[1]) + (s8[2] + s8[3]);
}

static __device__ __forceinline__ float blockMaxF(float a, double* s8) {
    for (int s = 32; s > 0; s >>= 1) a = fmaxf(a, __shfl_down(a, s, 64));
    const int w = threadIdx.x >> 6, l = threadIdx.x & 63;
    __syncthreads();
    if (l == 0) s8[w] = (double)a;
    __syncthreads();
    return fmaxf(fmaxf((float)s8[0], (float)s8[1]), fmaxf((float)s8[2], (float)s8[3]));
}

// ---------------- kernels ----------------

__global__ void init_kernel(unsigned int* ws_u) {
    int t = threadIdx.x;             // single block of 1024
    if (t == 0) ws_u[0] = 0u;
    if (t < NBINS) ws_u[4 + t] = 0u;
}

__global__ __launch_bounds__(256) void absmax_kernel(const float* __restrict__ x,
                                                     long long n,
                                                     unsigned int* absmax_bits) {
    __shared__ float red[256];
    float m = 0.f;
    long long idx = (long long)blockIdx.x * blockDim.x + threadIdx.x;
    long long stride = (long long)gridDim.x * blockDim.x;
    const float4* x4 = (const float4*)x;
    long long n4 = n >> 2;
    for (long long i = idx; i < n4; i += stride) {
        float4 v = x4[i];
        m = fmaxf(m, fmaxf(fmaxf(fabsf(v.x), fabsf(v.y)), fmaxf(fabsf(v.z), fabsf(v.w))));
    }
    for (long long i = (n4 << 2) + idx; i < n; i += stride)
        m = fmaxf(m, fabsf(x[i]));
    red[threadIdx.x] = m;
    __syncthreads();
    for (int s = 128; s > 0; s >>= 1) {
        if (threadIdx.x < s) red[threadIdx.x] = fmaxf(red[threadIdx.x], red[threadIdx.x + s]);
        __syncthreads();
    }
    if (threadIdx.x == 0) atomicMax(absmax_bits, __float_as_uint(red[0]));
}

static __device__ __forceinline__ void bin_one(float v, float inv, float cofs,
                                               float stepv, float negabs,
                                               unsigned int* __restrict__ sh) {
    // fast initial guess (fma ok: straight-line correction below restores exact
    // searchsorted semantics; guess provably within +/-1 of exact bin)
    float t = __builtin_fmaf(v, inv, cofs);
    int b = (int)t;
    b = b < 0 ? 0 : (b > NBINS - 1 ? NBINS - 1 : b);
    float e_lo = edge_at(b, stepv, negabs);
    float e_hi = edge_at(b + 1, stepv, negabs);
    int up = (v >= e_hi) & (b < NBINS - 1);
    int dn = (v < e_lo) & (b > 0);
    b += up - dn;
    atomicAdd(&sh[b], 1u);
}

__global__ __launch_bounds__(256) void hist_kernel(const float* __restrict__ x,
                                                   long long n,
                                                   const unsigned int* __restrict__ absmax_bits,
                                                   unsigned int* __restrict__ hist) {
    __shared__ unsigned int sh[4 * NBINS];   // per-wave private histograms (16 KB)
    for (int i = threadIdx.x; i < 4 * NBINS; i += blockDim.x) sh[i] = 0u;
    __syncthreads();
    unsigned int* mysh = sh + (threadIdx.x >> 6) * NBINS;

    float absmax = __uint_as_float(*absmax_bits);
    float negabs = -absmax;
    float stepv = __fdiv_rn(__fmul_rn(2.0f, absmax), 1001.0f);
    float inv = __fdiv_rn(1001.0f, __fmul_rn(2.0f, absmax));
    float cofs = __fmul_rn(absmax, inv);

    long long idx = (long long)blockIdx.x * blockDim.x + threadIdx.x;
    long long stride = (long long)gridDim.x * blockDim.x;
    const float4* x4 = (const float4*)x;
    long long n4 = n >> 2;
    for (long long i = idx; i < n4; i += stride) {
        float4 v = x4[i];
        bin_one(v.x, inv, cofs, stepv, negabs, mysh);
        bin_one(v.y, inv, cofs, stepv, negabs, mysh);
        bin_one(v.z, inv, cofs, stepv, negabs, mysh);
        bin_one(v.w, inv, cofs, stepv, negabs, mysh);
    }
    for (long long i = (n4 << 2) + idx; i < n; i += stride)
        bin_one(x[i], inv, cofs, stepv, negabs, mysh);

    __syncthreads();
    for (int i = threadIdx.x; i < NBINS; i += blockDim.x) {
        unsigned int s = sh[i] + sh[NBINS + i] + sh[2 * NBINS + i] + sh[3 * NBINS + i];
        if (s) atomicAdd(&hist[i], s);
    }
}

__global__ __launch_bounds__(256) void cand_kernel(const unsigned int* __restrict__ hist,
                                                   float* __restrict__ divg) {
    const int i = IMIN + (int)blockIdx.x;   // 63..500
    const int L = 2 * i + 1;                // 127..1001
    const int start = HALFB - i;
    const int stop = start + L;
    const int m = L / KQ;                   // 1..7
    const int tid = threadIdx.x;

    __shared__ float s_h[NBINS];
    __shared__ float s_qb[KQ];
    __shared__ int s_norm[KQ];
    __shared__ double s8[8];

    for (int k = tid; k < NBINS; k += 256) s_h[k] = (float)hist[k];
    if (tid < KQ) { s_qb[tid] = 0.f; s_norm[tid] = 0; }
    __syncthreads();

    // left = sum hist[0:start], right = sum hist[stop:1001]
    double lsum = 0.0, rsum = 0.0;
    for (int k = tid; k < start; k += 256) lsum += (double)s_h[k];
    for (int k = stop + tid; k < NBINS; k += 256) rsum += (double)s_h[k];
    blockSum2(lsum, rsum, s8);
    float left = (float)lsum, right = (float)rsum;

    // pass 1: sliced values, p-logit precursors, segment sums
    float sl[4], ppre[4];
    float zp = 0.f;                 // count of p==0 among valid
    float maxppre = -INFINITY;
#pragma unroll
    for (int j = 0; j < 4; ++j) {
        int k = tid + 256 * j;
        sl[j] = 0.f; ppre[j] = 0.f;
        if (k < L) {
            float s = s_h[start + k];
            sl[j] = s;
            int seg = k / m; if (seg > KQ - 1) seg = KQ - 1;
            atomicAdd(&s_qb[seg], s);
            if (s != 0.f && k != L - 1) atomicAdd(&s_norm[seg], 1);
            float p = s;
            if (k == 0) p += left;
            if (k == L - 1) p += right;
            float pp = (p == 0.f) ? SEPS : p;   // p + EPS*is_zero
            ppre[j] = pp;
            if (p == 0.f) zp += 1.f;
            maxppre = fmaxf(maxppre, pp);
        }
    }
    __syncthreads();   // s_qb / s_norm final

    double zpd = (double)zp;
    double nnzd = (tid < KQ) ? (double)s_norm[tid] : 0.0;
    blockSum2(zpd, nnzd, s8);
    float n_zeros_p = (float)zpd;
    int nnzq = (int)nnzd;
    float maxp = blockMaxF(maxppre, s8);

    // smoothing constants, f32 as in reference
    float n_nz_p = (float)L - n_zeros_p;
    float eps1p = SEPS * n_zeros_p / fmaxf(n_nz_p, 1.0f);
    float cp = eps1p * n_nz_p;

    float n_zeros_q = (float)L - (float)nnzq;   // q nonzero <=> (sliced!=0 && k!=L-1)
    float n_nz_qf = (float)L - n_zeros_q;
    float eps1q = SEPS * n_zeros_q / fmaxf(n_nz_qf, 1.0f);
    float cq = eps1q * n_nz_qf;

    // pass 2: q-logit precursors
    float qpre[4];
    float maxqpre = -INFINITY;
#pragma unroll
    for (int j = 0; j < 4; ++j) {
        int k = tid + 256 * j;
        qpre[j] = 0.f;
        if (k < L) {
            float s = sl[j];
            int seg = k / m; if (seg > KQ - 1) seg = KQ - 1;
            float qv = 0.f;
            int nk = s_norm[seg];
            if (s != 0.f && k != L - 1 && nk > 0) qv = s_qb[seg] / (float)nk;
            float qq = (qv == 0.f) ? SEPS : qv;
            qpre[j] = qq;
            maxqpre = fmaxf(maxqpre, qq);
        }
    }
    float maxq = blockMaxF(maxqpre, s8);
    float maxplog = maxp - cp;
    float maxqlog = maxq - cq;

    // pass 3: logsumexp sums
    double sp = 0.0, sq = 0.0;
#pragma unroll
    for (int j = 0; j < 4; ++j) {
        int k = tid + 256 * j;
        if (k < L) {
            sp += (double)expf((ppre[j] - cp) - maxplog);
            sq += (double)expf((qpre[j] - cq) - maxqlog);
        }
    }
    blockSum2(sp, sq, s8);
    float lZp = maxplog + (float)log(sp);
    float lZq = maxqlog + (float)log(sq);

    // pass 4: KL
    double kll = 0.0;
#pragma unroll
    for (int j = 0; j < 4; ++j) {
        int k = tid + 256 * j;
        if (k < L) {
            float pl = ppre[j] - cp;
            float ql = qpre[j] - cq;
            float lp = pl - lZp;
            float lq = ql - lZq;
            kll += (double)(expf(lp) * (lp - lq));
        }
    }
    double KL = blockSum1(kll, s8);
    if (tid == 0) divg[blockIdx.x] = (nnzq > 0) ? (float)KL : INFINITY;
}

__global__ void argmin_kernel(const float* __restrict__ divg,
                              const unsigned int* __restrict__ absmax_bits,
                              float* __restrict__ out) {
    __shared__ float vals[512];
    __shared__ int idxs[512];
    int tid = threadIdx.x;
    vals[tid] = (tid < NCAND) ? divg[tid] : INFINITY;
    idxs[tid] = tid;
    __syncthreads();
    for (int s = 256; s > 0; s >>= 1) {
        if (tid < s) {
            float a = vals[tid], b = vals[tid + s];
            int ia = idxs[tid], ib = idxs[tid + s];
            if (b < a || (b == a && ib < ia)) { vals[tid] = b; idxs[tid] = ib; }
        }
        __syncthreads();
    }
    if (tid == 0) {
        int i = IMIN + idxs[0];
        int stop = HALFB + i + 1;
        float absmax = __uint_as_float(*absmax_bits);
        float stepv = __fdiv_rn(__fmul_rn(2.0f, absmax), 1001.0f);
        out[0] = __fadd_rn(__fmul_rn((float)stop, stepv), -absmax);
    }
}

extern "C" void kernel_launch(void* const* d_in, const int* in_sizes, int n_in,
                              void* d_out, int out_size, void* d_ws, size_t ws_size,
                              hipStream_t stream) {
    const float* x = (const float*)d_in[0];
    long long n = (long long)in_sizes[0];

    unsigned int* ws_u = (unsigned int*)d_ws;
    unsigned int* absmax_bits = ws_u;                 // word 0
    unsigned int* hist = ws_u + 4;                    // words 4 .. 4+1001
    float* divg = (float*)(ws_u + 1028);              // words 1028 .. 1028+438
    float* out = (float*)d_out;

    hipLaunchKernelGGL(init_kernel, dim3(1), dim3(1024), 0, stream, ws_u);
    hipLaunchKernelGGL(absmax_kernel, dim3(2048), dim3(256), 0, stream, x, n, absmax_bits);
    hipLaunchKernelGGL(hist_kernel, dim3(1024), dim3(256), 0, stream, x, n, absmax_bits, hist);
    hipLaunchKernelGGL(cand_kernel, dim3(NCAND), dim3(256), 0, stream, hist, divg);
    hipLaunchKernelGGL(argmin_kernel, dim3(1), dim3(512), 0, stream, divg, absmax_bits, out);
}

// Round 4
// 256.470 us; speedup vs baseline: 1.2609x; 1.0065x over previous
//
#include <hip/hip_runtime.h>
#include <math.h>

#define NBINS 1001
#define KQ 127
#define HALFB 500
#define SEPS 1e-4f
#define NCAND 438   // i = 63 .. 500
#define IMIN 63

// ---------- ws layout (uint words) ----------
// ws_u[0]             : absmax bits (float as uint; |x|>=0 so uint order == float order)
// ws_u[4..1005)       : histogram counts (uint, 1001)
// ws_u[1028..1466)    : divergence[438] (float)
// ws_u[1536..3540)    : csumD[1002] (double, exclusive prefix of f32(hist))
// ws_u[3544..4546)    : nzc[1002]  (int, exclusive prefix of hist!=0)

static __device__ __forceinline__ float edge_at(int j, float stepv, float negabs) {
    // linspace semantics: edges[j] = j*step + (-absmax), separate rn mul/add (no fma)
    return __fadd_rn(__fmul_rn((float)j, stepv), negabs);
}

// ---------------- block reduction helpers (blockDim.x == 256 = 4 waves) ----------------
static __device__ __forceinline__ void blockSum2(double& a, double& b, double* s8) {
    for (int s = 32; s > 0; s >>= 1) {
        a += __shfl_down(a, s, 64);
        b += __shfl_down(b, s, 64);
    }
    const int w = threadIdx.x >> 6, l = threadIdx.x & 63;
    __syncthreads();
    if (l == 0) { s8[w] = a; s8[4 + w] = b; }
    __syncthreads();
    a = (s8[0] + s8[1]) + (s8[2] + s8[3]);
    b = (s8[4] + s8[5]) + (s8[6] + s8[7]);
}

static __device__ __forceinline__ double blockSum1(double a, double* s8) {
    for (int s = 32; s > 0; s >>= 1) a += __shfl_down(a, s, 64);
    const int w = threadIdx.x >> 6, l = threadIdx.x & 63;
    __syncthreads();
    if (l == 0) s8[w] = a;
    __syncthreads();
    return (s8[0] + s8[1]) + (s8[2] + s8[3]);
}

static __device__ __forceinline__ void blockMax2(float& a, float& b, double* s8) {
    for (int s = 32; s > 0; s >>= 1) {
        a = fmaxf(a, __shfl_down(a, s, 64));
        b = fmaxf(b, __shfl_down(b, s, 64));
    }
    const int w = threadIdx.x >> 6, l = threadIdx.x & 63;
    __syncthreads();
    if (l == 0) { s8[w] = (double)a; s8[4 + w] = (double)b; }
    __syncthreads();
    a = fmaxf(fmaxf((float)s8[0], (float)s8[1]), fmaxf((float)s8[2], (float)s8[3]));
    b = fmaxf(fmaxf((float)s8[4], (float)s8[5]), fmaxf((float)s8[6], (float)s8[7]));
}

// ---------------- kernels ----------------

__global__ void init_kernel(unsigned int* ws_u) {
    int t = threadIdx.x;             // single block of 1024
    if (t == 0) ws_u[0] = 0u;
    if (t < NBINS) ws_u[4 + t] = 0u;
}

__global__ __launch_bounds__(256) void absmax_kernel(const float* __restrict__ x,
                                                     long long n,
                                                     unsigned int* absmax_bits) {
    __shared__ float red[256];
    float m = 0.f;
    long long idx = (long long)blockIdx.x * blockDim.x + threadIdx.x;
    long long stride = (long long)gridDim.x * blockDim.x;
    const float4* x4 = (const float4*)x;
    long long n4 = n >> 2;
    long long i = idx;
    for (; i + stride < n4; i += 2 * stride) {
        float4 a = x4[i];
        float4 b = x4[i + stride];
        m = fmaxf(m, fmaxf(fmaxf(fabsf(a.x), fabsf(a.y)), fmaxf(fabsf(a.z), fabsf(a.w))));
        m = fmaxf(m, fmaxf(fmaxf(fabsf(b.x), fabsf(b.y)), fmaxf(fabsf(b.z), fabsf(b.w))));
    }
    for (; i < n4; i += stride) {
        float4 a = x4[i];
        m = fmaxf(m, fmaxf(fmaxf(fabsf(a.x), fabsf(a.y)), fmaxf(fabsf(a.z), fabsf(a.w))));
    }
    for (long long j = (n4 << 2) + idx; j < n; j += stride)
        m = fmaxf(m, fabsf(x[j]));
    red[threadIdx.x] = m;
    __syncthreads();
    for (int s = 128; s > 0; s >>= 1) {
        if (threadIdx.x < s) red[threadIdx.x] = fmaxf(red[threadIdx.x], red[threadIdx.x + s]);
        __syncthreads();
    }
    if (threadIdx.x == 0) atomicMax(absmax_bits, __float_as_uint(red[0]));
}

static __device__ __forceinline__ void bin_one(float v, float inv, float cofs,
                                               float stepv, float negabs,
                                               unsigned int* __restrict__ sh) {
    // fast fma guess; straight-line +/-1 correction restores exact searchsorted
    // semantics (guess provably within 1 of exact bin)
    float t = __builtin_fmaf(v, inv, cofs);
    int b = (int)t;
    b = b < 0 ? 0 : (b > NBINS - 1 ? NBINS - 1 : b);
    float e_lo = edge_at(b, stepv, negabs);
    float e_hi = edge_at(b + 1, stepv, negabs);
    int up = (v >= e_hi) & (b < NBINS - 1);
    int dn = (v < e_lo) & (b > 0);
    b += up - dn;
    atomicAdd(&sh[b], 1u);
}

__global__ __launch_bounds__(256) void hist_kernel(const float* __restrict__ x,
                                                   long long n,
                                                   const unsigned int* __restrict__ absmax_bits,
                                                   unsigned int* __restrict__ hist) {
    __shared__ unsigned int sh[4 * NBINS];   // per-wave private histograms (16 KB)
    for (int i = threadIdx.x; i < 4 * NBINS; i += blockDim.x) sh[i] = 0u;
    __syncthreads();
    unsigned int* mysh = sh + (threadIdx.x >> 6) * NBINS;

    float absmax = __uint_as_float(*absmax_bits);
    float negabs = -absmax;
    float stepv = __fdiv_rn(__fmul_rn(2.0f, absmax), 1001.0f);
    float inv = __fdiv_rn(1001.0f, __fmul_rn(2.0f, absmax));
    float cofs = __fmul_rn(absmax, inv);

    long long idx = (long long)blockIdx.x * blockDim.x + threadIdx.x;
    long long stride = (long long)gridDim.x * blockDim.x;
    const float4* x4 = (const float4*)x;
    long long n4 = n >> 2;
    long long i = idx;
    for (; i + stride < n4; i += 2 * stride) {
        float4 a = x4[i];
        float4 b = x4[i + stride];
        bin_one(a.x, inv, cofs, stepv, negabs, mysh);
        bin_one(a.y, inv, cofs, stepv, negabs, mysh);
        bin_one(a.z, inv, cofs, stepv, negabs, mysh);
        bin_one(a.w, inv, cofs, stepv, negabs, mysh);
        bin_one(b.x, inv, cofs, stepv, negabs, mysh);
        bin_one(b.y, inv, cofs, stepv, negabs, mysh);
        bin_one(b.z, inv, cofs, stepv, negabs, mysh);
        bin_one(b.w, inv, cofs, stepv, negabs, mysh);
    }
    for (; i < n4; i += stride) {
        float4 a = x4[i];
        bin_one(a.x, inv, cofs, stepv, negabs, mysh);
        bin_one(a.y, inv, cofs, stepv, negabs, mysh);
        bin_one(a.z, inv, cofs, stepv, negabs, mysh);
        bin_one(a.w, inv, cofs, stepv, negabs, mysh);
    }
    for (long long j = (n4 << 2) + idx; j < n; j += stride)
        bin_one(x[j], inv, cofs, stepv, negabs, mysh);

    __syncthreads();
    for (int i2 = threadIdx.x; i2 < NBINS; i2 += blockDim.x) {
        unsigned int s = sh[i2] + sh[NBINS + i2] + sh[2 * NBINS + i2] + sh[3 * NBINS + i2];
        if (s) atomicAdd(&hist[i2], s);
    }
}

// exclusive prefix sums over f32-rounded counts (double) and nonzero flags (int)
__global__ __launch_bounds__(1024) void scan_kernel(const unsigned int* __restrict__ hist,
                                                    double* __restrict__ csumD,
                                                    int* __restrict__ nzc) {
    __shared__ double sd[1024];
    __shared__ int si[1024];
    int t = threadIdx.x;
    unsigned int h = (t < NBINS) ? hist[t] : 0u;
    sd[t] = (double)((float)h);          // f32-round counts like reference astype(float32)
    si[t] = (t < NBINS && h != 0u) ? 1 : 0;
    __syncthreads();
    for (int off = 1; off < 1024; off <<= 1) {
        double dv = 0.0; int iv = 0;
        if (t >= off) { dv = sd[t - off]; iv = si[t - off]; }
        __syncthreads();
        sd[t] += dv; si[t] += iv;
        __syncthreads();
    }
    // sd/si now inclusive; emit exclusive with total at [NBINS]
    if (t < NBINS) { csumD[t + 1] = sd[t]; nzc[t + 1] = si[t]; }
    if (t == 0) { csumD[0] = 0.0; nzc[0] = 0; }
}

__global__ __launch_bounds__(256) void cand_kernel(const unsigned int* __restrict__ hist,
                                                   const double* __restrict__ csumD,
                                                   const int* __restrict__ nzc,
                                                   float* __restrict__ divg) {
    const int i = IMIN + (int)blockIdx.x;   // 63..500
    const int L = 2 * i + 1;                // 127..1001
    const int start = HALFB - i;
    const int stop = start + L;
    const int m = L / KQ;                   // 1..7
    const unsigned int magic = (65536u + (unsigned)m - 1u) / (unsigned)m;  // k/m = (k*magic)>>16, k<=1000
    const int tid = threadIdx.x;

    __shared__ float s_h[NBINS];
    __shared__ float s_qb[KQ];
    __shared__ float s_nkf[KQ];
    __shared__ double s8[8];

    for (int k = tid; k < NBINS; k += 256) s_h[k] = (float)hist[k];

    // ---- scalar prework (no reductions needed) ----
    double csS = csumD[start], csE = csumD[stop], total = csumD[NBINS];
    float left = (float)csS;
    float right = (float)(total - csE);
    float s0 = (float)hist[start];
    float sL1 = (float)hist[stop - 1];
    int nzwin = nzc[stop] - nzc[start];         // # nonzero sliced in window
    int nnzq = nzwin - ((sL1 != 0.f) ? 1 : 0);  // q nonzero <=> s!=0 && k!=L-1
    int nzeros_s = L - nzwin;
    // p==0 iff s==0 and (k!=0 or left==0) and (k!=L-1 or right==0)
    float n_zeros_p = (float)(nzeros_s
                              - ((s0 == 0.f && csS > 0.0) ? 1 : 0)
                              - ((sL1 == 0.f && (total - csE) > 0.0) ? 1 : 0));

    float n_nz_p = (float)L - n_zeros_p;
    float eps1p = SEPS * n_zeros_p / fmaxf(n_nz_p, 1.0f);
    float cp = eps1p * n_nz_p;

    float n_zeros_q = (float)L - (float)nnzq;
    float n_nz_qf = (float)L - n_zeros_q;
    float eps1q = SEPS * n_zeros_q / fmaxf(n_nz_qf, 1.0f);
    float cq = eps1q * n_nz_qf;

    // ---- segment sums from prefix arrays (no atomics) ----
    if (tid < KQ) {
        int lo = start + tid * m;
        int hi = (tid == KQ - 1) ? stop : (lo + m);
        s_qb[tid] = (float)(csumD[hi] - csumD[lo]);
        int nrm = (nzc[hi] - nzc[lo]) - ((tid == KQ - 1 && sL1 != 0.f) ? 1 : 0);
        s_nkf[tid] = (float)nrm;
    }
    __syncthreads();   // covers s_h, s_qb, s_nkf

    // ---- pass 1: logit precursors + maxes ----
    float ppre[4], qpre[4];
    float maxpp = -INFINITY, maxqq = -INFINITY;
#pragma unroll
    for (int j = 0; j < 4; ++j) {
        int k = tid + 256 * j;
        ppre[j] = 0.f; qpre[j] = 0.f;
        if (k < L) {
            float s = s_h[start + k];
            float p = s;
            if (k == 0) p += left;
            if (k == L - 1) p += right;
            float pp = (p == 0.f) ? SEPS : p;
            int seg = (int)(((unsigned)k * magic) >> 16);
            if (seg > KQ - 1) seg = KQ - 1;   // remainder bins -> last merged bin (the R3 bug)
            float qv = 0.f;
            if (s != 0.f && k != L - 1) {
                float nk = s_nkf[seg];
                if (nk > 0.f) qv = s_qb[seg] / nk;
            }
            float qq = (qv == 0.f) ? SEPS : qv;
            ppre[j] = pp; qpre[j] = qq;
            maxpp = fmaxf(maxpp, pp);
            maxqq = fmaxf(maxqq, qq);
        }
    }
    blockMax2(maxpp, maxqq, s8);
    float maxplog = maxpp - cp;
    float maxqlog = maxqq - cq;

    // ---- pass 2: logsumexp sums ----
    double sp = 0.0, sq = 0.0;
#pragma unroll
    for (int j = 0; j < 4; ++j) {
        int k = tid + 256 * j;
        if (k < L) {
            sp += (double)expf((ppre[j] - cp) - maxplog);
            sq += (double)expf((qpre[j] - cq) - maxqlog);
        }
    }
    blockSum2(sp, sq, s8);
    float lZp = maxplog + (float)log(sp);
    float lZq = maxqlog + (float)log(sq);

    // ---- pass 3: KL ----
    double kll = 0.0;
#pragma unroll
    for (int j = 0; j < 4; ++j) {
        int k = tid + 256 * j;
        if (k < L) {
            float pl = ppre[j] - cp;
            float ql = qpre[j] - cq;
            float lp = pl - lZp;
            float lq = ql - lZq;
            kll += (double)(expf(lp) * (lp - lq));
        }
    }
    double KL = blockSum1(kll, s8);
    if (tid == 0) divg[blockIdx.x] = (nnzq > 0) ? (float)KL : INFINITY;
}

__global__ void argmin_kernel(const float* __restrict__ divg,
                              const unsigned int* __restrict__ absmax_bits,
                              float* __restrict__ out) {
    __shared__ float vals[512];
    __shared__ int idxs[512];
    int tid = threadIdx.x;
    vals[tid] = (tid < NCAND) ? divg[tid] : INFINITY;
    idxs[tid] = tid;
    __syncthreads();
    for (int s = 256; s > 0; s >>= 1) {
        if (tid < s) {
            float a = vals[tid], b = vals[tid + s];
            int ia = idxs[tid], ib = idxs[tid + s];
            if (b < a || (b == a && ib < ia)) { vals[tid] = b; idxs[tid] = ib; }
        }
        __syncthreads();
    }
    if (tid == 0) {
        int i = IMIN + idxs[0];
        int stop = HALFB + i + 1;
        float absmax = __uint_as_float(*absmax_bits);
        float stepv = __fdiv_rn(__fmul_rn(2.0f, absmax), 1001.0f);
        out[0] = __fadd_rn(__fmul_rn((float)stop, stepv), -absmax);
    }
}

extern "C" void kernel_launch(void* const* d_in, const int* in_sizes, int n_in,
                              void* d_out, int out_size, void* d_ws, size_t ws_size,
                              hipStream_t stream) {
    const float* x = (const float*)d_in[0];
    long long n = (long long)in_sizes[0];

    unsigned int* ws_u = (unsigned int*)d_ws;
    unsigned int* absmax_bits = ws_u;                 // word 0
    unsigned int* hist = ws_u + 4;                    // words 4 .. 1005
    float* divg = (float*)(ws_u + 1028);              // words 1028 .. 1466
    double* csumD = (double*)(ws_u + 1536);           // words 1536 .. 3540
    int* nzc = (int*)(ws_u + 3544);                   // words 3544 .. 4546
    float* out = (float*)d_out;

    hipLaunchKernelGGL(init_kernel, dim3(1), dim3(1024), 0, stream, ws_u);
    hipLaunchKernelGGL(absmax_kernel, dim3(2048), dim3(256), 0, stream, x, n, absmax_bits);
    hipLaunchKernelGGL(hist_kernel, dim3(1024), dim3(256), 0, stream, x, n, absmax_bits, hist);
    hipLaunchKernelGGL(scan_kernel, dim3(1), dim3(1024), 0, stream, hist, csumD, nzc);
    hipLaunchKernelGGL(cand_kernel, dim3(NCAND), dim3(256), 0, stream, hist, csumD, nzc, divg);
    hipLaunchKernelGGL(argmin_kernel, dim3(1), dim3(512), 0, stream, divg, absmax_bits, out);
}